// Round 4
// baseline (22.785 us; speedup 1.0000x reference)
//
#include <hip/hip_runtime.h>
#include <math.h>

#define NP 5
#define NH 64
#define BLK 256

typedef float f32x2  __attribute__((ext_vector_type(2)));
typedef float f32x16 __attribute__((ext_vector_type(16)));

#define LOG2E 1.44269504088896340736f
// -2y(z)*log2(e) = z*(-C_CDF0 - C_CDF1*z^2),  2y = 1.5957691*(z + 0.044715 z^3)
#define C_CDF0 2.30220840f
#define C_CDF1 0.10294324f
// d(2y)/dz = C_G2A + C_G2B*z^2
#define C_G2A 1.59576912f
#define C_G2B 0.21406460f
// phi(z)=exp2(C_PDF_A*z^2 + C_PDF_B)  (exact Gaussian, 1/sqrt(2pi) folded)
#define C_PDF_A (-0.72134752f)
#define C_PDF_B (-1.32574806f)

// ---- prep: pack per-unit weights pair-interleaved into ws ----
// layout: pair pp (k=2pp,2pp+1) at ws[pp*16 .. pp*16+15]:
//   {w0.lo,w0.hi, w1.lo,w1.hi, w2.lo,w2.hi, w3.lo,w3.hi,
//    w4.lo,w4.hi, b1.lo,b1.hi, wo.lo,wo.hi, sw.lo,sw.hi}  sw=0.2*sum(w^2)*wo
// ws[512..516]=gamma  ws[517..521]=beta  ws[522..533]=Wc  ws[534]=b2 ws[535]=bc
__global__ __launch_bounds__(64) void prep_kernel(
    const float* __restrict__ gW1, const float* __restrict__ gb1,
    const float* __restrict__ gW2, const float* __restrict__ gb2,
    const float* __restrict__ gLng, const float* __restrict__ gLnb,
    const float* __restrict__ gWc, const float* __restrict__ gbc,
    float* __restrict__ ws)
{
    const int k = threadIdx.x;                 // 0..63
    float w0 = gW1[k],        w1 = gW1[NH + k], w2 = gW1[2*NH + k];
    float w3 = gW1[3*NH + k], w4 = gW1[4*NH + k];
    float bb = gb1[k], wo = gW2[k];
    float s  = w0*w0 + w1*w1 + w2*w2 + w3*w3 + w4*w4;
    float sw = 0.2f * s * wo;
    const int base = (k >> 1) * 16 + (k & 1);
    ws[base + 0]  = w0;  ws[base + 2]  = w1;
    ws[base + 4]  = w2;  ws[base + 6]  = w3;
    ws[base + 8]  = w4;  ws[base + 10] = bb;
    ws[base + 12] = wo;  ws[base + 14] = sw;
    if (k < NP)  { ws[512 + k] = gLng[k]; ws[517 + k] = gLnb[k]; }
    if (k < 12)  ws[522 + k] = gWc[k];
    if (k == 0)  { ws[534] = gb2[0]; ws[535] = gbc[0]; }
}

// scalar (SMEM) load of one 64B pair-record; early-clobber so dst never
// aliases the base pointer regs while the load is in flight
#define SLOAD(Q, OFF) \
    asm volatile("s_load_dwordx16 %0, %1, %2" : "=&s"(Q) : "s"(wsp), "n"(OFF))
// SMEM completion is unordered -> only lgkmcnt(0) is safe; sched_barrier(0)
// stops consumers being hoisted above the wait (rule #18)
#define SWAIT() do { asm volatile("s_waitcnt lgkmcnt(0)" ::: "memory"); \
    __builtin_amdgcn_sched_barrier(0); } while (0)

__global__ __launch_bounds__(BLK) void topo_kernel(
    const float* __restrict__ pillars,
    const float* __restrict__ ws,
    float* __restrict__ out,
    int n)
{
    const int t = threadIdx.x;
    const long sidx = (long)blockIdx.x * BLK + t;
    if (sidx >= n) return;

    // epilogue / LN constants (uniform, L1/K$-hot)
    float gam[NP], bet[NP], wcf[12];
    #pragma unroll
    for (int j = 0; j < NP; ++j) { gam[j] = ws[512 + j]; bet[j] = ws[517 + j]; }
    #pragma unroll
    for (int i = 0; i < 12; ++i) wcf[i] = ws[522 + i];
    const float b2v = ws[534], bcv = ws[535];

    // per-sample pillars (20B/lane, contiguous across lanes)
    const float* prow = pillars + sidx * NP;
    float raw[NP], p[NP], x[NP];
    #pragma unroll
    for (int j = 0; j < NP; ++j) raw[j] = prow[j];

    float mu = 0.f;
    #pragma unroll
    for (int j = 0; j < NP; ++j) {
        float v = raw[j];
        if (!(v == v)) v = 0.5f;          // NaN -> 0.5
        v = fminf(fmaxf(v, 0.f), 1.f);    // clip
        p[j] = v; mu += v;
    }
    mu *= 0.2f;
    float var = 0.f;
    #pragma unroll
    for (int j = 0; j < NP; ++j) { float d = p[j] - mu; var += d * d; }
    var *= 0.2f;
    float inv = rsqrtf(var + 1e-5f);
    #pragma unroll
    for (int j = 0; j < NP; ++j) x[j] = (p[j] - mu) * inv * gam[j] + bet[j];

    f32x2 P[NP], X[NP];
    #pragma unroll
    for (int j = 0; j < NP; ++j) { P[j] = (f32x2){p[j], p[j]}; X[j] = (f32x2){x[j], x[j]}; }

    const f32x2 one = {1.f, 1.f}, two = {2.f, 2.f};
    const f32x2 cC0 = {-C_CDF0, -C_CDF0}, cC1 = {-C_CDF1, -C_CDF1};
    const f32x2 cGA = {C_G2A, C_G2A},     cGB = {C_G2B, C_G2B};
    const f32x2 cPA = {C_PDF_A, C_PDF_A}, cPB = {C_PDF_B, C_PDF_B};

    f32x2 V2 = {0.f,0.f}, TR = {0.f,0.f};
    f32x2 G0 = {0.f,0.f}, G1 = {0.f,0.f}, G2 = {0.f,0.f}, G3 = {0.f,0.f}, G4 = {0.f,0.f};

    const float* wsp = ws;      // SGPR base for SMEM loads
    f32x16 qA, qB;
    SLOAD(qA, 0);

#define BODY(Q)                                                              \
    do {                                                                     \
        f32x2 w0 = {Q[0],Q[1]},  w1 = {Q[2],Q[3]},  w2 = {Q[4],Q[5]};        \
        f32x2 w3 = {Q[6],Q[7]},  w4 = {Q[8],Q[9]},  bb = {Q[10],Q[11]};      \
        f32x2 wo = {Q[12],Q[13]}, sw = {Q[14],Q[15]};                        \
        f32x2 z  = P[0]*w0 + (P[1]*w1 + (P[2]*w2 + (P[3]*w3 + (P[4]*w4 + bb)))); \
        f32x2 zx = X[0]*w0 + (X[1]*w1 + (X[2]*w2 + (X[3]*w3 + (X[4]*w4 + bb)))); \
        f32x2 tz = z * z;                                                    \
        f32x2 tx = zx * zx;                                                  \
        f32x2 ya = z * (tz * cC1 + cC0);                                     \
        f32x2 e;                                                             \
        e.x = __builtin_amdgcn_exp2f(ya.x);                                  \
        e.y = __builtin_amdgcn_exp2f(ya.y);                                  \
        f32x2 ope = e + one;                                                 \
        f32x2 s;                                                             \
        s.x = __builtin_amdgcn_rcpf(ope.x);                                  \
        s.y = __builtin_amdgcn_rcpf(ope.y);                                  \
        V2 = (z * s) * wo + V2;                                              \
        f32x2 u   = s - s * s;                                               \
        f32x2 g2p = tz * cGB + cGA;                                          \
        f32x2 d1  = ((z * u) * g2p + s) * wo;                                \
        G0 = w0 * d1 + G0; G1 = w1 * d1 + G1; G2 = w2 * d1 + G2;             \
        G3 = w3 * d1 + G3; G4 = w4 * d1 + G4;                                \
        f32x2 pa = tx * cPA + cPB;                                           \
        f32x2 ph;                                                            \
        ph.x = __builtin_amdgcn_exp2f(pa.x);                                 \
        ph.y = __builtin_amdgcn_exp2f(pa.y);                                 \
        TR = (sw * (two - tx)) * ph + TR;                                    \
    } while (0)

    #pragma unroll
    for (int pp = 0; pp < 32; ++pp) {
        SWAIT();                               // drain: current pair ready
        if (pp & 1) {
            if (pp < 31) SLOAD(qA, ((pp + 1) * 64));
            BODY(qB);
        } else {
            if (pp < 31) SLOAD(qB, ((pp + 1) * 64));
            BODY(qA);
        }
    }
#undef BODY

    float V = V2.x + V2.y + b2v;
    float emean = TR.x + TR.y;          // 0.2 folded into sw

    float f[12];
    f[0] = raw[0]; f[1] = raw[1]; f[2] = raw[2]; f[3] = raw[3]; f[4] = raw[4];
    f[5] = G0.x + G0.y; f[6] = G1.x + G1.y; f[7] = G2.x + G2.y;
    f[8] = G3.x + G3.y; f[9] = G4.x + G4.y;
    f[10] = V; f[11] = emean;

    float nrm = 0.f;
    #pragma unroll
    for (int i = 0; i < 12; ++i) nrm = fmaf(f[i], f[i], nrm);
    float denom = fmaxf(sqrtf(nrm), 1e-12f);
    float dot = 0.f;
    #pragma unroll
    for (int i = 0; i < 12; ++i) dot = fmaf(f[i], wcf[i], dot);
    float sarg = dot * __builtin_amdgcn_rcpf(denom) + bcv;
    float es = __builtin_amdgcn_exp2f(-sarg * LOG2E);
    float prob = __builtin_amdgcn_rcpf(1.0f + es);
    prob = fminf(fmaxf(prob, 0.f), 1.f);
    out[sidx] = prob;
}

extern "C" void kernel_launch(void* const* d_in, const int* in_sizes, int n_in,
                              void* d_out, int out_size, void* d_ws, size_t ws_size,
                              hipStream_t stream) {
    const float* pillars = (const float*)d_in[0];
    const float* W1  = (const float*)d_in[1];
    const float* b1  = (const float*)d_in[2];
    const float* W2  = (const float*)d_in[3];
    const float* b2  = (const float*)d_in[4];
    const float* lng = (const float*)d_in[5];
    const float* lnb = (const float*)d_in[6];
    const float* Wc  = (const float*)d_in[7];
    const float* bc  = (const float*)d_in[8];
    float* out = (float*)d_out;
    float* ws  = (float*)d_ws;          // needs 536 floats

    prep_kernel<<<1, 64, 0, stream>>>(W1, b1, W2, b2, lng, lnb, Wc, bc, ws);

    const int n = in_sizes[0] / NP;     // 262144
    const int blocks = (n + BLK - 1) / BLK;
    topo_kernel<<<blocks, BLK, 0, stream>>>(pillars, ws, out, n);
}

// Round 5
// 19.109 us; speedup vs baseline: 1.1924x; 1.1924x over previous
//
#include <hip/hip_runtime.h>
#include <math.h>

#define NP 5
#define NH 64
#define BLK 256

typedef float f32x2 __attribute__((ext_vector_type(2)));

#define LOG2E 1.44269504088896340736f
// -2y(z)*log2(e) = z*(-C_CDF0 - C_CDF1*z^2),  2y = 1.5957691*(z + 0.044715 z^3)
#define C_CDF0 2.30220840f
#define C_CDF1 0.10294324f
// d(2y)/dz = C_G2A + C_G2B*z^2
#define C_G2A 1.59576912f
#define C_G2B 0.21406460f
// phi(z)=exp2(C_PDF_A*z^2 + C_PDF_B)  (exact Gaussian, 1/sqrt(2pi) folded)
#define C_PDF_A (-0.72134752f)
#define C_PDF_B (-1.32574806f)

__global__ __launch_bounds__(BLK) void topo_kernel(
    const float* __restrict__ pillars,
    const float* __restrict__ gW1,   // [5][64]
    const float* __restrict__ gb1,   // [64]
    const float* __restrict__ gW2,   // [64]
    const float* __restrict__ gb2,   // [1]
    const float* __restrict__ gLng,  // [5]
    const float* __restrict__ gLnb,  // [5]
    const float* __restrict__ gWc,   // [12]
    const float* __restrict__ gbc,   // [1]
    float* __restrict__ out,
    int n)
{
    const int t = threadIdx.x;
    const long sidx = (long)blockIdx.x * BLK + t;
    if (sidx >= n) return;

    // uniform constants -> scalar loads (K$-hot)
    float gam[NP], bet[NP], wcf[12];
    #pragma unroll
    for (int j = 0; j < NP; ++j) { gam[j] = gLng[j]; bet[j] = gLnb[j]; }
    #pragma unroll
    for (int i = 0; i < 12; ++i) wcf[i] = gWc[i];
    const float b2v = gb2[0], bcv = gbc[0];

    // per-sample pillars: 5 consecutive floats, lanes stride 20B (L1-coalesced)
    const float* prow = pillars + sidx * NP;
    float raw[NP], p[NP], x[NP];
    #pragma unroll
    for (int j = 0; j < NP; ++j) raw[j] = prow[j];

    float mu = 0.f;
    #pragma unroll
    for (int j = 0; j < NP; ++j) {
        float v = raw[j];
        if (!(v == v)) v = 0.5f;          // NaN -> 0.5
        v = fminf(fmaxf(v, 0.f), 1.f);    // clip (handles +/-inf)
        p[j] = v; mu += v;
    }
    mu *= 0.2f;
    float var = 0.f;
    #pragma unroll
    for (int j = 0; j < NP; ++j) { float d = p[j] - mu; var += d * d; }
    var *= 0.2f;
    float inv = rsqrtf(var + 1e-5f);
    #pragma unroll
    for (int j = 0; j < NP; ++j) x[j] = (p[j] - mu) * inv * gam[j] + bet[j];

    f32x2 P[NP], X[NP];
    #pragma unroll
    for (int j = 0; j < NP; ++j) { P[j] = (f32x2){p[j], p[j]}; X[j] = (f32x2){x[j], x[j]}; }

    const f32x2 one = {1.f, 1.f}, two = {2.f, 2.f};
    const f32x2 cC0 = {-C_CDF0, -C_CDF0}, cC1 = {-C_CDF1, -C_CDF1};
    const f32x2 cGA = {C_G2A, C_G2A},     cGB = {C_G2B, C_G2B};
    const f32x2 cPA = {C_PDF_A, C_PDF_A}, cPB = {C_PDF_B, C_PDF_B};

    f32x2 V2 = {0.f,0.f}, TR = {0.f,0.f};
    f32x2 G0 = {0.f,0.f}, G1 = {0.f,0.f}, G2 = {0.f,0.f}, G3 = {0.f,0.f}, G4 = {0.f,0.f};

    // weights read at wave-uniform addresses -> compiler emits s_load_*,
    // schedules/batches them itself (no LDS, no syncthreads, no asm drains)
    #pragma unroll 4
    for (int pp = 0; pp < 32; ++pp) {
        const int k0 = 2 * pp;
        f32x2 w0 = {gW1[0*NH + k0], gW1[0*NH + k0 + 1]};
        f32x2 w1 = {gW1[1*NH + k0], gW1[1*NH + k0 + 1]};
        f32x2 w2 = {gW1[2*NH + k0], gW1[2*NH + k0 + 1]};
        f32x2 w3 = {gW1[3*NH + k0], gW1[3*NH + k0 + 1]};
        f32x2 w4 = {gW1[4*NH + k0], gW1[4*NH + k0 + 1]};
        f32x2 bb = {gb1[k0], gb1[k0 + 1]};
        f32x2 wo = {gW2[k0], gW2[k0 + 1]};

        // sw = (sum_j w_j^2) * wo   (0.2 folded into epilogue)
        f32x2 ssum = w0*w0 + (w1*w1 + (w2*w2 + (w3*w3 + w4*w4)));
        f32x2 sw = ssum * wo;

        f32x2 z  = P[0]*w0 + (P[1]*w1 + (P[2]*w2 + (P[3]*w3 + (P[4]*w4 + bb))));
        f32x2 zx = X[0]*w0 + (X[1]*w1 + (X[2]*w2 + (X[3]*w3 + (X[4]*w4 + bb))));

        f32x2 tz = z * z;
        f32x2 tx = zx * zx;

        // sigma(2y) via exp2
        f32x2 ya = z * (tz * cC1 + cC0);
        f32x2 e;
        e.x = __builtin_amdgcn_exp2f(ya.x);
        e.y = __builtin_amdgcn_exp2f(ya.y);
        f32x2 ope = e + one;
        f32x2 s;
        s.x = __builtin_amdgcn_rcpf(ope.x);
        s.y = __builtin_amdgcn_rcpf(ope.y);

        V2 = (z * s) * wo + V2;                       // gelu(z)*W2
        f32x2 u   = s - s * s;                        // sigma*(1-sigma)
        f32x2 g2p = tz * cGB + cGA;                   // d(2y)/dz
        f32x2 d1  = ((z * u) * g2p + s) * wo;         // gelu'(z)*W2
        G0 = w0 * d1 + G0; G1 = w1 * d1 + G1; G2 = w2 * d1 + G2;
        G3 = w3 * d1 + G3; G4 = w4 * d1 + G4;

        // trace: sw*(2 - zx^2)*phi(zx)  (phi exact, exp2 domain)
        f32x2 pa = tx * cPA + cPB;
        f32x2 ph;
        ph.x = __builtin_amdgcn_exp2f(pa.x);
        ph.y = __builtin_amdgcn_exp2f(pa.y);
        TR = (sw * (two - tx)) * ph + TR;
    }

    float V = V2.x + V2.y + b2v;
    float emean = 0.2f * (TR.x + TR.y);

    float f[12];
    f[0] = raw[0]; f[1] = raw[1]; f[2] = raw[2]; f[3] = raw[3]; f[4] = raw[4];
    f[5] = G0.x + G0.y; f[6] = G1.x + G1.y; f[7] = G2.x + G2.y;
    f[8] = G3.x + G3.y; f[9] = G4.x + G4.y;
    f[10] = V; f[11] = emean;

    float nrm = 0.f;
    #pragma unroll
    for (int i = 0; i < 12; ++i) nrm = fmaf(f[i], f[i], nrm);
    float denom = fmaxf(sqrtf(nrm), 1e-12f);
    float dot = 0.f;
    #pragma unroll
    for (int i = 0; i < 12; ++i) dot = fmaf(f[i], wcf[i], dot);
    float sarg = dot * __builtin_amdgcn_rcpf(denom) + bcv;
    float es = __builtin_amdgcn_exp2f(-sarg * LOG2E);
    float prob = __builtin_amdgcn_rcpf(1.0f + es);
    prob = fminf(fmaxf(prob, 0.f), 1.f);
    out[sidx] = prob;
}

extern "C" void kernel_launch(void* const* d_in, const int* in_sizes, int n_in,
                              void* d_out, int out_size, void* d_ws, size_t ws_size,
                              hipStream_t stream) {
    const float* pillars = (const float*)d_in[0];
    const float* W1  = (const float*)d_in[1];
    const float* b1  = (const float*)d_in[2];
    const float* W2  = (const float*)d_in[3];
    const float* b2  = (const float*)d_in[4];
    const float* lng = (const float*)d_in[5];
    const float* lnb = (const float*)d_in[6];
    const float* Wc  = (const float*)d_in[7];
    const float* bc  = (const float*)d_in[8];
    float* out = (float*)d_out;

    const int n = in_sizes[0] / NP;     // 262144
    const int blocks = (n + BLK - 1) / BLK;
    topo_kernel<<<blocks, BLK, 0, stream>>>(
        pillars, W1, b1, W2, b2, lng, lnb, Wc, bc, out, n);
}